// Round 18
// baseline (1048.522 us; speedup 1.0000x reference)
//
#include <hip/hip_runtime.h>
#include <math.h>

#define SLOPE 0.01f

typedef __attribute__((ext_vector_type(8))) short bf16x8;
typedef __attribute__((ext_vector_type(4))) float f32x4;
typedef unsigned short ushort_t;

__device__ __forceinline__ float lrelu(float x) {
    return x > 0.f ? x : SLOPE * x;
}

__device__ __forceinline__ unsigned short f2bf(float f) {
    unsigned int u = __float_as_uint(f);
    u += 0x7fffu + ((u >> 16) & 1u);
    return (unsigned short)(u >> 16);
}

__device__ __forceinline__ float bf2f(unsigned short u) {
    return __uint_as_float((unsigned int)u << 16);
}

// ---------------------------------------------------------------------------
// Merged f32 -> bf16 conversion for ALL weights (dst buffers contiguous).
// Segments (vec4 units): fc1w 3612672 | fc2w 65536 | wih 262144 | whh 262144
// | dfw 16384 | dw 2048  -> total 4220928.
// ---------------------------------------------------------------------------
__global__ void cvt_all_kernel(const float* __restrict__ s0,
                               const float* __restrict__ s1,
                               const float* __restrict__ s2,
                               const float* __restrict__ s3,
                               const float* __restrict__ s4,
                               const float* __restrict__ s5,
                               unsigned short* __restrict__ dst) {
    int i = blockIdx.x * blockDim.x + threadIdx.x;
    if (i >= 4220928) return;
    const float* src; int base;
    if (i < 3612672)      { src = s0; base = 0; }
    else if (i < 3678208) { src = s1; base = 3612672; }
    else if (i < 3940352) { src = s2; base = 3678208; }
    else if (i < 4202496) { src = s3; base = 3940352; }
    else if (i < 4218880) { src = s4; base = 4202496; }
    else                  { src = s5; base = 4218880; }
    float4 v = ((const float4*)src)[i - base];
    uint2 o;
    o.x = (unsigned)f2bf(v.x) | ((unsigned)f2bf(v.y) << 16);
    o.y = (unsigned)f2bf(v.z) | ((unsigned)f2bf(v.w) << 16);
    ((uint2*)dst)[i] = o;
}

// ---------------------------------------------------------------------------
// conv1 (5x5), LDS-tiled, scalar-pipe weights. (unchanged R17)
// ---------------------------------------------------------------------------
template<int K, bool INBF, bool OUTBF>
__global__ __launch_bounds__(256) void conv_tile_kernel(
        const void* __restrict__ in_v,
        const float* __restrict__ w,
        const float* __restrict__ b,
        void* __restrict__ out_v) {
    constexpr int HALO = K / 2;
    constexpr int TILE_H = 12;
    constexpr int SH = TILE_H + 2 * HALO;
    constexpr int SW = 88;
    __shared__ float smem[4][SH][SW];

    int tid = threadIdx.x;
    int n = blockIdx.x;
    int row0 = blockIdx.y * TILE_H;
    const size_t imgOff = (size_t)n * (4 * 84 * 84);

    for (int it = tid; it < 4 * SH * 22; it += 256) {
        int item = it % 22;
        int rr = it / 22;
        int r = rr % SH;
        int ci = rr / SH;
        int gr = row0 + r - HALO;
        bool rv = (unsigned)gr < 84u;
        if (item < 21) {
            int gc = item * 4;
            float4 v = make_float4(0.f, 0.f, 0.f, 0.f);
            if (rv) {
                size_t off = imgOff + ((size_t)ci * 84 + gr) * 84 + gc;
                if (INBF) {
                    unsigned long long u =
                        *(const unsigned long long*)((const ushort_t*)in_v + off);
                    v.x = bf2f((unsigned short)u);
                    v.y = bf2f((unsigned short)(u >> 16));
                    v.z = bf2f((unsigned short)(u >> 32));
                    v.w = bf2f((unsigned short)(u >> 48));
                } else {
                    v = *(const float4*)((const float*)in_v + off);
                }
            }
            smem[ci][r][HALO + gc + 0] = v.x;
            smem[ci][r][HALO + gc + 1] = v.y;
            smem[ci][r][HALO + gc + 2] = v.z;
            smem[ci][r][HALO + gc + 3] = v.w;
        } else {
            if (HALO == 2) {
                smem[ci][r][0] = 0.f; smem[ci][r][1] = 0.f;
                smem[ci][r][86] = 0.f; smem[ci][r][87] = 0.f;
            } else {
                smem[ci][r][0] = 0.f;
                smem[ci][r][85] = 0.f; smem[ci][r][86] = 0.f; smem[ci][r][87] = 0.f;
            }
        }
    }
    __syncthreads();

    if (tid >= 252) return;
    int r  = tid / 21;
    int w0 = (tid % 21) * 4;

    float acc[4][4];
    #pragma unroll
    for (int co = 0; co < 4; ++co) {
        float bv = b[co];
        #pragma unroll
        for (int dw = 0; dw < 4; ++dw) acc[co][dw] = bv;
    }

    #pragma unroll
    for (int ci = 0; ci < 4; ++ci) {
        #pragma unroll
        for (int kh = 0; kh < K; ++kh) {
            float vals[K + 3];
            float4 v0 = *(const float4*)&smem[ci][r + kh][w0];
            vals[0] = v0.x; vals[1] = v0.y; vals[2] = v0.z; vals[3] = v0.w;
            if (K == 5) {
                float4 v1 = *(const float4*)&smem[ci][r + kh][w0 + 4];
                vals[4] = v1.x; vals[5] = v1.y; vals[6] = v1.z; vals[7] = v1.w;
            } else {
                float2 v1 = *(const float2*)&smem[ci][r + kh][w0 + 4];
                vals[4] = v1.x; vals[5] = v1.y;
            }
            #pragma unroll
            for (int co = 0; co < 4; ++co) {
                #pragma unroll
                for (int kw = 0; kw < K; ++kw) {
                    float wv = w[((co * 4 + ci) * K + kh) * K + kw];
                    #pragma unroll
                    for (int dw = 0; dw < 4; ++dw)
                        acc[co][dw] += vals[kw + dw] * wv;
                }
            }
        }
    }

    int oh = row0 + r;
    #pragma unroll
    for (int co = 0; co < 4; ++co) {
        size_t off = imgOff + ((size_t)co * 84 + oh) * 84 + w0;
        float o0 = lrelu(acc[co][0]);
        float o1 = lrelu(acc[co][1]);
        float o2 = lrelu(acc[co][2]);
        float o3 = lrelu(acc[co][3]);
        if (OUTBF) {
            uint2 p;
            p.x = (unsigned)f2bf(o0) | ((unsigned)f2bf(o1) << 16);
            p.y = (unsigned)f2bf(o2) | ((unsigned)f2bf(o3) << 16);
            *(uint2*)((ushort_t*)out_v + off) = p;
        } else {
            *(float4*)((float*)out_v + off) = make_float4(o0, o1, o2, o3);
        }
    }
}

// ---------------------------------------------------------------------------
// Fused conv2(3x3)+conv3(3x3): bf16 in -> bf16 out, mid stays f32 in LDS.
// Grid (2048, 6 row-tiles of 14), block 384. Two separate LDS buffers (NO
// aliasing), single-shot compute phases, scalar-pipe weights (R17-proven).
// ---------------------------------------------------------------------------
__global__ __launch_bounds__(384) void conv23_fused_kernel(
        const ushort_t* __restrict__ in_b,
        const float* __restrict__ w2, const float* __restrict__ b2,
        const float* __restrict__ w3, const float* __restrict__ b3,
        unsigned short* __restrict__ out) {
    __shared__ float ins[4][18][88];   // conv2 input rows r0-2..r0+15
    __shared__ float mid[4][16][88];   // conv2 output rows r0-1..r0+14

    int tid = threadIdx.x;
    int n = blockIdx.x;
    int r0 = blockIdx.y * 14;
    const size_t imgOff = (size_t)n * (4 * 84 * 84);

    // P0: stage input strip (bf16 -> f32), zero halos
    for (int it = tid; it < 4 * 18 * 22; it += 384) {
        int item = it % 22;
        int rr = it / 22;
        int r = rr % 18;
        int ci = rr / 18;
        int gr = r0 - 2 + r;
        bool rv = (unsigned)gr < 84u;
        if (item < 21) {
            int gc = item * 4;
            float4 v = make_float4(0.f, 0.f, 0.f, 0.f);
            if (rv) {
                unsigned long long u = *(const unsigned long long*)
                    (in_b + imgOff + ((size_t)ci * 84 + gr) * 84 + gc);
                v.x = bf2f((unsigned short)u);
                v.y = bf2f((unsigned short)(u >> 16));
                v.z = bf2f((unsigned short)(u >> 32));
                v.w = bf2f((unsigned short)(u >> 48));
            }
            ins[ci][r][1 + gc + 0] = v.x;
            ins[ci][r][1 + gc + 1] = v.y;
            ins[ci][r][1 + gc + 2] = v.z;
            ins[ci][r][1 + gc + 3] = v.w;
        } else {
            ins[ci][r][0] = 0.f;
            ins[ci][r][85] = 0.f; ins[ci][r][86] = 0.f; ins[ci][r][87] = 0.f;
        }
    }
    __syncthreads();

    // P1: conv2 -> mid (16 rows; rows outside image zeroed; halo cols zeroed)
    if (tid < 128) {
        int co = tid >> 5; int rr = (tid & 31) >> 1; int cc = (tid & 1) ? 85 : 0;
        mid[co][rr][cc] = 0.f;
    }
    if (tid < 336) {
        int m  = tid / 21;
        int c0 = (tid % 21) * 4;
        int gm = r0 - 1 + m;
        float acc[4][4];
        #pragma unroll
        for (int co = 0; co < 4; ++co) {
            float bv = b2[co];
            #pragma unroll
            for (int dw = 0; dw < 4; ++dw) acc[co][dw] = bv;
        }
        #pragma unroll
        for (int ci = 0; ci < 4; ++ci) {
            #pragma unroll
            for (int kh = 0; kh < 3; ++kh) {
                float vals[6];
                float4 v0 = *(const float4*)&ins[ci][m + kh][c0];
                float2 v1 = *(const float2*)&ins[ci][m + kh][c0 + 4];
                vals[0] = v0.x; vals[1] = v0.y; vals[2] = v0.z; vals[3] = v0.w;
                vals[4] = v1.x; vals[5] = v1.y;
                #pragma unroll
                for (int co = 0; co < 4; ++co) {
                    #pragma unroll
                    for (int kw = 0; kw < 3; ++kw) {
                        float wv = w2[((co * 4 + ci) * 3 + kh) * 3 + kw];
                        #pragma unroll
                        for (int dw = 0; dw < 4; ++dw)
                            acc[co][dw] += vals[kw + dw] * wv;
                    }
                }
            }
        }
        bool valid = (unsigned)gm < 84u;
        #pragma unroll
        for (int co = 0; co < 4; ++co)
            #pragma unroll
            for (int dw = 0; dw < 4; ++dw)
                mid[co][m][1 + c0 + dw] = valid ? lrelu(acc[co][dw]) : 0.f;
    }
    __syncthreads();

    // P2: conv3 -> global bf16 (14 rows)
    if (tid < 294) {
        int ro = tid / 21;
        int c0 = (tid % 21) * 4;
        float acc[4][4];
        #pragma unroll
        for (int co = 0; co < 4; ++co) {
            float bv = b3[co];
            #pragma unroll
            for (int dw = 0; dw < 4; ++dw) acc[co][dw] = bv;
        }
        #pragma unroll
        for (int ci = 0; ci < 4; ++ci) {
            #pragma unroll
            for (int kh = 0; kh < 3; ++kh) {
                float vals[6];
                float4 v0 = *(const float4*)&mid[ci][ro + kh][c0];
                float2 v1 = *(const float2*)&mid[ci][ro + kh][c0 + 4];
                vals[0] = v0.x; vals[1] = v0.y; vals[2] = v0.z; vals[3] = v0.w;
                vals[4] = v1.x; vals[5] = v1.y;
                #pragma unroll
                for (int co = 0; co < 4; ++co) {
                    #pragma unroll
                    for (int kw = 0; kw < 3; ++kw) {
                        float wv = w3[((co * 4 + ci) * 3 + kh) * 3 + kw];
                        #pragma unroll
                        for (int dw = 0; dw < 4; ++dw)
                            acc[co][dw] += vals[kw + dw] * wv;
                    }
                }
            }
        }
        int go = r0 + ro;
        #pragma unroll
        for (int co = 0; co < 4; ++co) {
            float o0 = lrelu(acc[co][0]);
            float o1 = lrelu(acc[co][1]);
            float o2 = lrelu(acc[co][2]);
            float o3 = lrelu(acc[co][3]);
            uint2 p;
            p.x = (unsigned)f2bf(o0) | ((unsigned)f2bf(o1) << 16);
            p.y = (unsigned)f2bf(o2) | ((unsigned)f2bf(o3) << 16);
            *(uint2*)(out + imgOff + ((size_t)co * 84 + go) * 84 + c0) = p;
        }
    }
}

// ---------------------------------------------------------------------------
// bf16 MFMA GEMM (NT) with epilogue (fc2, heads). (unchanged)
// ---------------------------------------------------------------------------
template<bool DO_LRELU, bool BIAS2, bool OUTBF>
__global__ void gemm_bf16_kernel(const unsigned short* __restrict__ A,
                                 const unsigned short* __restrict__ B,
                                 const float* __restrict__ bias,
                                 const float* __restrict__ bias2,
                                 void* __restrict__ Cout,
                                 int M, int N, int K) {
    __shared__ unsigned short As[64][40];
    __shared__ unsigned short Bs[64][40];
    int tid = threadIdx.x;
    int rowBase = blockIdx.y * 64;
    int colBase = blockIdx.x * 64;

    int wave = tid >> 6;
    int l    = tid & 63;
    int wr = wave >> 1, wc = wave & 1;
    int lane16 = l & 15;
    int kb = (l >> 4) * 8;

    int sr = tid >> 2;
    int sk = (tid & 3) << 3;
    const unsigned short* Ap = A + (size_t)(rowBase + sr) * K + sk;
    const unsigned short* Bp = B + (size_t)(colBase + sr) * K + sk;

    f32x4 acc[2][2] = {};

    for (int k0 = 0; k0 < K; k0 += 32) {
        float4 av = *(const float4*)(Ap + k0);
        float4 bv = *(const float4*)(Bp + k0);
        __syncthreads();
        *(float4*)(&As[sr][sk]) = av;
        *(float4*)(&Bs[sr][sk]) = bv;
        __syncthreads();
        bf16x8 a0 = *(const bf16x8*)(&As[wr * 32 + lane16][kb]);
        bf16x8 a1 = *(const bf16x8*)(&As[wr * 32 + 16 + lane16][kb]);
        bf16x8 b0 = *(const bf16x8*)(&Bs[wc * 32 + lane16][kb]);
        bf16x8 b1 = *(const bf16x8*)(&Bs[wc * 32 + 16 + lane16][kb]);
        acc[0][0] = __builtin_amdgcn_mfma_f32_16x16x32_bf16(a0, b0, acc[0][0], 0, 0, 0);
        acc[0][1] = __builtin_amdgcn_mfma_f32_16x16x32_bf16(a0, b1, acc[0][1], 0, 0, 0);
        acc[1][0] = __builtin_amdgcn_mfma_f32_16x16x32_bf16(a1, b0, acc[1][0], 0, 0, 0);
        acc[1][1] = __builtin_amdgcn_mfma_f32_16x16x32_bf16(a1, b1, acc[1][1], 0, 0, 0);
    }

    int crow0 = rowBase + wr * 32 + (l >> 4) * 4;
    int ccol0 = colBase + wc * 32 + lane16;
    float bsv[2];
    #pragma unroll
    for (int j = 0; j < 2; ++j) {
        bsv[j] = bias[ccol0 + j * 16];
        if (BIAS2) bsv[j] += bias2[ccol0 + j * 16];
    }
    #pragma unroll
    for (int i = 0; i < 2; ++i) {
        #pragma unroll
        for (int r = 0; r < 4; ++r) {
            int row = crow0 + i * 16 + r;
            #pragma unroll
            for (int j = 0; j < 2; ++j) {
                float v = acc[i][j][r] + bsv[j];
                if (DO_LRELU) v = lrelu(v);
                size_t off = (size_t)row * N + ccol0 + j * 16;
                if (OUTBF) ((unsigned short*)Cout)[off] = f2bf(v);
                else       ((float*)Cout)[off] = v;
            }
        }
    }
}

// ---------------------------------------------------------------------------
// Split-K bf16 MFMA GEMM: writes f32 partials. (unchanged)
// ---------------------------------------------------------------------------
__global__ void gemm_bf16_splitk_kernel(const unsigned short* __restrict__ A,
                                        const unsigned short* __restrict__ B,
                                        float* __restrict__ part,
                                        int M, int N, int K, int kChunk) {
    __shared__ unsigned short As[64][40];
    __shared__ unsigned short Bs[64][40];
    int tid = threadIdx.x;
    int rowBase = blockIdx.y * 64;
    int colBase = blockIdx.x * 64;
    int s = blockIdx.z;
    int kStart = s * kChunk;
    int kEnd = kStart + kChunk;

    int wave = tid >> 6;
    int l    = tid & 63;
    int wr = wave >> 1, wc = wave & 1;
    int lane16 = l & 15;
    int kb = (l >> 4) * 8;

    int sr = tid >> 2;
    int sk = (tid & 3) << 3;
    const unsigned short* Ap = A + (size_t)(rowBase + sr) * K + sk;
    const unsigned short* Bp = B + (size_t)(colBase + sr) * K + sk;

    f32x4 acc[2][2] = {};

    for (int k0 = kStart; k0 < kEnd; k0 += 32) {
        float4 av = *(const float4*)(Ap + k0);
        float4 bv = *(const float4*)(Bp + k0);
        __syncthreads();
        *(float4*)(&As[sr][sk]) = av;
        *(float4*)(&Bs[sr][sk]) = bv;
        __syncthreads();
        bf16x8 a0 = *(const bf16x8*)(&As[wr * 32 + lane16][kb]);
        bf16x8 a1 = *(const bf16x8*)(&As[wr * 32 + 16 + lane16][kb]);
        bf16x8 b0 = *(const bf16x8*)(&Bs[wc * 32 + lane16][kb]);
        bf16x8 b1 = *(const bf16x8*)(&Bs[wc * 32 + 16 + lane16][kb]);
        acc[0][0] = __builtin_amdgcn_mfma_f32_16x16x32_bf16(a0, b0, acc[0][0], 0, 0, 0);
        acc[0][1] = __builtin_amdgcn_mfma_f32_16x16x32_bf16(a0, b1, acc[0][1], 0, 0, 0);
        acc[1][0] = __builtin_amdgcn_mfma_f32_16x16x32_bf16(a1, b0, acc[1][0], 0, 0, 0);
        acc[1][1] = __builtin_amdgcn_mfma_f32_16x16x32_bf16(a1, b1, acc[1][1], 0, 0, 0);
    }

    float* Cp = part + (size_t)s * M * N;
    int crow0 = rowBase + wr * 32 + (l >> 4) * 4;
    int ccol0 = colBase + wc * 32 + lane16;
    #pragma unroll
    for (int i = 0; i < 2; ++i)
        #pragma unroll
        for (int r = 0; r < 4; ++r) {
            int row = crow0 + i * 16 + r;
            #pragma unroll
            for (int j = 0; j < 2; ++j)
                Cp[(size_t)row * N + ccol0 + j * 16] = acc[i][j][r];
        }
}

// ---------------------------------------------------------------------------
// Split-K reduce. (S=9)
// ---------------------------------------------------------------------------
template<int S>
__global__ void splitk_reduce_kernel(const float* __restrict__ part,
                                     const float* __restrict__ bias,
                                     unsigned short* __restrict__ out,
                                     int MN, int N) {
    int i4 = blockIdx.x * blockDim.x + threadIdx.x;
    if (i4 * 4 >= MN) return;
    float4 acc = ((const float4*)part)[i4];
    #pragma unroll
    for (int s = 1; s < S; ++s) {
        float4 p = ((const float4*)(part + (size_t)s * MN))[i4];
        acc.x += p.x; acc.y += p.y; acc.z += p.z; acc.w += p.w;
    }
    int col4 = i4 % (N / 4);
    float4 bv = ((const float4*)bias)[col4];
    float o0 = lrelu(acc.x + bv.x);
    float o1 = lrelu(acc.y + bv.y);
    float o2 = lrelu(acc.z + bv.z);
    float o3 = lrelu(acc.w + bv.w);
    uint2 p;
    p.x = (unsigned)f2bf(o0) | ((unsigned)f2bf(o1) << 16);
    p.y = (unsigned)f2bf(o2) | ((unsigned)f2bf(o3) << 16);
    ((uint2*)out)[i4] = p;
}

// ---------------------------------------------------------------------------
// LSTM init: HA (bf16) = h0; zero barrier counters.
// ---------------------------------------------------------------------------
__global__ void lstm_init_kernel(const float* __restrict__ h0,
                                 unsigned short* __restrict__ HA,
                                 int* __restrict__ bar) {
    int i = blockIdx.x * blockDim.x + threadIdx.x;
    if (i < 16384) HA[i] = f2bf(h0[i]);
    if (i < 64) bar[i] = 0;
}

// ---------------------------------------------------------------------------
// Persistent LSTM scan — R13/R17-proven counter barrier (244 µs floor).
// ---------------------------------------------------------------------------
__global__ __launch_bounds__(256, 1) void lstm_scan_kernel(
        const unsigned short* __restrict__ whh_b,   // [2048][512] bf16
        const unsigned short* __restrict__ wih_b,   // [2048][512] bf16
        const float* __restrict__ bih,
        const float* __restrict__ bhh,
        const unsigned short* __restrict__ HA,      // [32][512] bf16
        const float* __restrict__ c0,               // [32][512] f32
        const unsigned short* __restrict__ hfc2,    // [2048][512] bf16
        const float* __restrict__ done,             // [2048] f32
        unsigned short* __restrict__ feat,          // [2048][512] bf16
        float* __restrict__ hN, float* __restrict__ cN,
        int* __restrict__ bar) {
    __shared__ float mds[2048];
    __shared__ float Gs[4][16][17];
    __shared__ unsigned short Hs[16][520];
    __shared__ unsigned short Xh[16][520];

    int tid = threadIdx.x;
    int jt = blockIdx.x >> 1;
    int bt = blockIdx.x & 1;

    for (int i = tid; i < 2048; i += 256) mds[i] = 1.0f - done[i];

    int g = tid >> 6;
    int l = tid & 63;
    int lane16 = l & 15;
    int khi = l >> 4;
    const unsigned short* Wp =
        whh_b + ((size_t)g * 512 + jt * 16 + lane16) * 512 + khi * 8;
    const unsigned short* Wxp =
        wih_b + ((size_t)g * 512 + jt * 16 + lane16) * 512 + khi * 8;
    bf16x8 wreg[16], wxreg[16];
    #pragma unroll
    for (int kk = 0; kk < 16; ++kk) {
        wreg[kk]  = *(const bf16x8*)(Wp + kk * 32);
        wxreg[kk] = *(const bf16x8*)(Wxp + kk * 32);
    }

    int jloc = tid & 15;
    int bloc = tid >> 4;
    int j = jt * 16 + jloc;
    int b = bt * 16 + bloc;
    float c_reg = c0[b * 512 + j];
    float bsv[4];
    #pragma unroll
    for (int gg = 0; gg < 4; ++gg)
        bsv[gg] = bih[gg * 512 + j] + bhh[gg * 512 + j];

    int* mybar = bar + bt * 32;

    {
        const float4* h4 = (const float4*)(HA + bt * 8192);
        const float4* x4 = (const float4*)(hfc2 + bt * 8192);
        #pragma unroll
        for (int u0 = 0; u0 < 4; ++u0) {
            int u = tid + u0 * 256;
            float4 hv = h4[u];
            float4 xv = x4[u];
            *(float4*)&Hs[u >> 6][(u & 63) * 8] = hv;
            *(float4*)&Xh[u >> 6][(u & 63) * 8] = xv;
        }
    }
    __syncthreads();

    for (int t = 0; t < 64; ++t) {
        f32x4 hacc0 = {}, hacc1 = {}, xacc0 = {}, xacc1 = {};
        #pragma unroll
        for (int kk = 0; kk < 16; kk += 2) {
            bf16x8 hb0 = *(const bf16x8*)(&Hs[lane16][khi * 8 + kk * 32]);
            bf16x8 hb1 = *(const bf16x8*)(&Hs[lane16][khi * 8 + kk * 32 + 32]);
            bf16x8 xb0 = *(const bf16x8*)(&Xh[lane16][khi * 8 + kk * 32]);
            bf16x8 xb1 = *(const bf16x8*)(&Xh[lane16][khi * 8 + kk * 32 + 32]);
            hacc0 = __builtin_amdgcn_mfma_f32_16x16x32_bf16(wreg[kk],      hb0, hacc0, 0, 0, 0);
            hacc1 = __builtin_amdgcn_mfma_f32_16x16x32_bf16(wreg[kk + 1],  hb1, hacc1, 0, 0, 0);
            xacc0 = __builtin_amdgcn_mfma_f32_16x16x32_bf16(wxreg[kk],     xb0, xacc0, 0, 0, 0);
            xacc1 = __builtin_amdgcn_mfma_f32_16x16x32_bf16(wxreg[kk + 1], xb1, xacc1, 0, 0, 0);
        }
        f32x4 hacc = hacc0 + hacc1;
        f32x4 xacc = xacc0 + xacc1;
        float mcol = mds[t * 32 + bt * 16 + lane16];
        #pragma unroll
        for (int r = 0; r < 4; ++r)
            Gs[g][khi * 4 + r][lane16] = xacc[r] + mcol * hacc[r];
        __syncthreads();

        float4 xv0, xv1, xv2, xv3;
        if (t < 63) {
            const float4* x4 =
                (const float4*)(hfc2 + (size_t)(t + 1) * 16384 + bt * 8192);
            xv0 = x4[tid];
            xv1 = x4[tid + 256];
            xv2 = x4[tid + 512];
            xv3 = x4[tid + 768];
        }

        int row = t * 32 + b;
        float m = mds[row];
        float ai = bsv[0] + Gs[0][jloc][bloc];
        float af = bsv[1] + Gs[1][jloc][bloc];
        float ag = bsv[2] + Gs[2][jloc][bloc];
        float ao = bsv[3] + Gs[3][jloc][bloc];
        float cp = c_reg * m;
        float si = 1.f / (1.f + __expf(-ai));
        float sf = 1.f / (1.f + __expf(-af));
        float so = 1.f / (1.f + __expf(-ao));
        c_reg = sf * cp + si * tanhf(ag);
        float hn = so * tanhf(c_reg);
        feat[(size_t)row * 512 + j] = f2bf(hn);
        if (t == 63) {
            hN[b * 512 + j] = hn;
            cN[b * 512 + j] = c_reg;
        }

        if (t < 63) {
            *(float4*)&Xh[tid >> 6][(tid & 63) * 8] = xv0;
            {
                int u = tid + 256;
                *(float4*)&Xh[u >> 6][(u & 63) * 8] = xv1;
                u = tid + 512;
                *(float4*)&Xh[u >> 6][(u & 63) * 8] = xv2;
                u = tid + 768;
                *(float4*)&Xh[u >> 6][(u & 63) * 8] = xv3;
            }
            __syncthreads();
            if (tid == 0) {
                int target = (t + 1) * 32;
                __hip_atomic_fetch_add(mybar, 1, __ATOMIC_ACQ_REL,
                                       __HIP_MEMORY_SCOPE_AGENT);
                while (__hip_atomic_load(mybar, __ATOMIC_RELAXED,
                                         __HIP_MEMORY_SCOPE_AGENT) < target)
                    __builtin_amdgcn_s_sleep(2);
                __builtin_amdgcn_fence(__ATOMIC_ACQUIRE, "agent");
            }
            __syncthreads();
            const float4* h4 =
                (const float4*)(feat + (size_t)t * 16384 + bt * 8192);
            #pragma unroll
            for (int u0 = 0; u0 < 4; ++u0) {
                int u = tid + u0 * 256;
                float4 hv = h4[u];
                *(float4*)&Hs[u >> 6][(u & 63) * 8] = hv;
            }
            __syncthreads();
        }
    }
}

// ---------------------------------------------------------------------------
extern "C" void kernel_launch(void* const* d_in, const int* in_sizes, int n_in,
                              void* d_out, int out_size, void* d_ws, size_t ws_size,
                              hipStream_t stream) {
    const float* x    = (const float*)d_in[0];
    const float* done = (const float*)d_in[1];
    const float* h0   = (const float*)d_in[2];
    const float* c0   = (const float*)d_in[3];
    const float* c1w  = (const float*)d_in[4];
    const float* c1b  = (const float*)d_in[5];
    const float* c2w  = (const float*)d_in[6];
    const float* c2b  = (const float*)d_in[7];
    const float* c3w  = (const float*)d_in[8];
    const float* c3b  = (const float*)d_in[9];
    const float* fc1w = (const float*)d_in[10];
    const float* fc1b = (const float*)d_in[11];
    const float* fc2w = (const float*)d_in[12];
    const float* fc2b = (const float*)d_in[13];
    const float* wih  = (const float*)d_in[14];
    const float* whh  = (const float*)d_in[15];
    const float* bih  = (const float*)d_in[16];
    const float* bhh  = (const float*)d_in[17];
    const float* dfw  = (const float*)d_in[18];
    const float* dfb  = (const float*)d_in[19];
    const float* dw   = (const float*)d_in[20];
    const float* db   = (const float*)d_in[21];
    float* out = (float*)d_out;

    const size_t CONV_ELEMS = 57802752;            // 2048*4*84*84
    char* S = (char*)d_ws;
    unsigned short* c1out  = (unsigned short*)S;   S += CONV_ELEMS * 2;
    unsigned short* c3out  = (unsigned short*)S;   S += CONV_ELEMS * 2;
    // contiguous weight region (cvt_all writes it as one flat array)
    unsigned short* fc1w_b = (unsigned short*)S;   S += 28901376;
    unsigned short* fc2w_b = (unsigned short*)S;   S += 524288;
    unsigned short* wih_b  = (unsigned short*)S;   S += 2097152;
    unsigned short* whh_b  = (unsigned short*)S;   S += 2097152;
    unsigned short* dfw_b  = (unsigned short*)S;   S += 131072;
    unsigned short* dw_b   = (unsigned short*)S;   S += 16384;
    unsigned short* hfc1_b = (unsigned short*)S;   S += 2097152;
    unsigned short* hfc2_b = (unsigned short*)S;   S += 2097152;
    unsigned short* feat_b = (unsigned short*)S;   S += 2097152;
    unsigned short* dfeat_b= (unsigned short*)S;   S += 524288;
    unsigned short* HA     = (unsigned short*)S;   S += 32768;
    float*          part   = (float*)S;            S += 37748736;  // 9x[2048][512] f32
    int*            bar    = (int*)S;              S += 256;

    // --- conv stack: conv1 + fused conv2/3 ---
    conv_tile_kernel<5, false, true><<<dim3(2048, 7), 256, 0, stream>>>(
        x, c1w, c1b, c1out);
    conv23_fused_kernel<<<dim3(2048, 6), 384, 0, stream>>>(
        c1out, c2w, c2b, c3w, c3b, c3out);

    // --- all weight conversions in one kernel (dst region contiguous) ---
    cvt_all_kernel<<<dim3((4220928 + 255) / 256), 256, 0, stream>>>(
        fc1w, fc2w, wih, whh, dfw, dw, fc1w_b);

    // --- fc1: split-K x9, then reduce+bias+lrelu ---
    gemm_bf16_splitk_kernel<<<dim3(8, 32, 9), 256, 0, stream>>>(
        c3out, fc1w_b, part, 2048, 512, 28224, 3136);
    splitk_reduce_kernel<9><<<dim3(1024), 256, 0, stream>>>(
        part, fc1b, hfc1_b, 1048576, 512);

    // --- fc2 ---
    gemm_bf16_kernel<true, false, true><<<dim3(8, 32), 256, 0, stream>>>(
        hfc1_b, fc2w_b, fc2b, nullptr, hfc2_b, 2048, 512, 512);

    // --- LSTM scan (single persistent launch; R13 barrier) ---
    lstm_init_kernel<<<dim3(64), 256, 0, stream>>>(h0, HA, bar);
    lstm_scan_kernel<<<dim3(64), 256, 0, stream>>>(
        whh_b, wih_b, bih, bhh, HA, c0, hfc2_b, done, feat_b,
        out + 131072, out + 131072 + 16384, bar);

    // --- discriminator head ---
    gemm_bf16_kernel<true, false, true><<<dim3(2, 32), 256, 0, stream>>>(
        feat_b, dfw_b, dfb, nullptr, dfeat_b, 2048, 128, 512);
    gemm_bf16_kernel<false, false, false><<<dim3(1, 32), 256, 0, stream>>>(
        dfeat_b, dw_b, db, nullptr, out, 2048, 64, 128);
}

// Round 19
// 826.692 us; speedup vs baseline: 1.2683x; 1.2683x over previous
//
#include <hip/hip_runtime.h>
#include <math.h>

#define SLOPE 0.01f

typedef __attribute__((ext_vector_type(8))) short bf16x8;
typedef __attribute__((ext_vector_type(4))) float f32x4;
typedef unsigned short ushort_t;

__device__ __forceinline__ float lrelu(float x) {
    return x > 0.f ? x : SLOPE * x;
}

__device__ __forceinline__ unsigned short f2bf(float f) {
    unsigned int u = __float_as_uint(f);
    u += 0x7fffu + ((u >> 16) & 1u);
    return (unsigned short)(u >> 16);
}

__device__ __forceinline__ float bf2f(unsigned short u) {
    return __uint_as_float((unsigned int)u << 16);
}

// ---------------------------------------------------------------------------
// Merged f32 -> bf16 conversion for ALL weights (dst buffers contiguous).
// Segments (vec4 units): fc1w 3612672 | fc2w 65536 | wih 262144 | whh 262144
// | dfw 16384 | dw 2048  -> total 4220928.
// ---------------------------------------------------------------------------
__global__ void cvt_all_kernel(const float* __restrict__ s0,
                               const float* __restrict__ s1,
                               const float* __restrict__ s2,
                               const float* __restrict__ s3,
                               const float* __restrict__ s4,
                               const float* __restrict__ s5,
                               unsigned short* __restrict__ dst) {
    int i = blockIdx.x * blockDim.x + threadIdx.x;
    if (i >= 4220928) return;
    const float* src; int base;
    if (i < 3612672)      { src = s0; base = 0; }
    else if (i < 3678208) { src = s1; base = 3612672; }
    else if (i < 3940352) { src = s2; base = 3678208; }
    else if (i < 4202496) { src = s3; base = 3940352; }
    else if (i < 4218880) { src = s4; base = 4202496; }
    else                  { src = s5; base = 4218880; }
    float4 v = ((const float4*)src)[i - base];
    uint2 o;
    o.x = (unsigned)f2bf(v.x) | ((unsigned)f2bf(v.y) << 16);
    o.y = (unsigned)f2bf(v.z) | ((unsigned)f2bf(v.w) << 16);
    ((uint2*)dst)[i] = o;
}

// ---------------------------------------------------------------------------
// LDS-tiled conv 4->4, SAME, kernel K, fused bias+LeakyReLU.
// R17-proven: vectorized staging, scalar-pipe weights, 52 VGPR, no spill.
// (3-stage and 2-stage fusions both rejected by measurement — R8/R10/R18.)
// ---------------------------------------------------------------------------
template<int K, bool INBF, bool OUTBF>
__global__ __launch_bounds__(256) void conv_tile_kernel(
        const void* __restrict__ in_v,
        const float* __restrict__ w,
        const float* __restrict__ b,
        void* __restrict__ out_v) {
    constexpr int HALO = K / 2;
    constexpr int TILE_H = 12;
    constexpr int SH = TILE_H + 2 * HALO;
    constexpr int SW = 88;
    __shared__ float smem[4][SH][SW];

    int tid = threadIdx.x;
    int n = blockIdx.x;
    int row0 = blockIdx.y * TILE_H;
    const size_t imgOff = (size_t)n * (4 * 84 * 84);

    for (int it = tid; it < 4 * SH * 22; it += 256) {
        int item = it % 22;
        int rr = it / 22;
        int r = rr % SH;
        int ci = rr / SH;
        int gr = row0 + r - HALO;
        bool rv = (unsigned)gr < 84u;
        if (item < 21) {
            int gc = item * 4;
            float4 v = make_float4(0.f, 0.f, 0.f, 0.f);
            if (rv) {
                size_t off = imgOff + ((size_t)ci * 84 + gr) * 84 + gc;
                if (INBF) {
                    unsigned long long u =
                        *(const unsigned long long*)((const ushort_t*)in_v + off);
                    v.x = bf2f((unsigned short)u);
                    v.y = bf2f((unsigned short)(u >> 16));
                    v.z = bf2f((unsigned short)(u >> 32));
                    v.w = bf2f((unsigned short)(u >> 48));
                } else {
                    v = *(const float4*)((const float*)in_v + off);
                }
            }
            smem[ci][r][HALO + gc + 0] = v.x;
            smem[ci][r][HALO + gc + 1] = v.y;
            smem[ci][r][HALO + gc + 2] = v.z;
            smem[ci][r][HALO + gc + 3] = v.w;
        } else {
            if (HALO == 2) {
                smem[ci][r][0] = 0.f; smem[ci][r][1] = 0.f;
                smem[ci][r][86] = 0.f; smem[ci][r][87] = 0.f;
            } else {
                smem[ci][r][0] = 0.f;
                smem[ci][r][85] = 0.f; smem[ci][r][86] = 0.f; smem[ci][r][87] = 0.f;
            }
        }
    }
    __syncthreads();

    if (tid >= 252) return;
    int r  = tid / 21;
    int w0 = (tid % 21) * 4;

    float acc[4][4];
    #pragma unroll
    for (int co = 0; co < 4; ++co) {
        float bv = b[co];
        #pragma unroll
        for (int dw = 0; dw < 4; ++dw) acc[co][dw] = bv;
    }

    #pragma unroll
    for (int ci = 0; ci < 4; ++ci) {
        #pragma unroll
        for (int kh = 0; kh < K; ++kh) {
            float vals[K + 3];
            float4 v0 = *(const float4*)&smem[ci][r + kh][w0];
            vals[0] = v0.x; vals[1] = v0.y; vals[2] = v0.z; vals[3] = v0.w;
            if (K == 5) {
                float4 v1 = *(const float4*)&smem[ci][r + kh][w0 + 4];
                vals[4] = v1.x; vals[5] = v1.y; vals[6] = v1.z; vals[7] = v1.w;
            } else {
                float2 v1 = *(const float2*)&smem[ci][r + kh][w0 + 4];
                vals[4] = v1.x; vals[5] = v1.y;
            }
            #pragma unroll
            for (int co = 0; co < 4; ++co) {
                #pragma unroll
                for (int kw = 0; kw < K; ++kw) {
                    float wv = w[((co * 4 + ci) * K + kh) * K + kw];
                    #pragma unroll
                    for (int dw = 0; dw < 4; ++dw)
                        acc[co][dw] += vals[kw + dw] * wv;
                }
            }
        }
    }

    int oh = row0 + r;
    #pragma unroll
    for (int co = 0; co < 4; ++co) {
        size_t off = imgOff + ((size_t)co * 84 + oh) * 84 + w0;
        float o0 = lrelu(acc[co][0]);
        float o1 = lrelu(acc[co][1]);
        float o2 = lrelu(acc[co][2]);
        float o3 = lrelu(acc[co][3]);
        if (OUTBF) {
            uint2 p;
            p.x = (unsigned)f2bf(o0) | ((unsigned)f2bf(o1) << 16);
            p.y = (unsigned)f2bf(o2) | ((unsigned)f2bf(o3) << 16);
            *(uint2*)((ushort_t*)out_v + off) = p;
        } else {
            *(float4*)((float*)out_v + off) = make_float4(o0, o1, o2, o3);
        }
    }
}

// ---------------------------------------------------------------------------
// bf16 MFMA GEMM (NT) with epilogue (fc2, heads). (unchanged)
// ---------------------------------------------------------------------------
template<bool DO_LRELU, bool BIAS2, bool OUTBF>
__global__ void gemm_bf16_kernel(const unsigned short* __restrict__ A,
                                 const unsigned short* __restrict__ B,
                                 const float* __restrict__ bias,
                                 const float* __restrict__ bias2,
                                 void* __restrict__ Cout,
                                 int M, int N, int K) {
    __shared__ unsigned short As[64][40];
    __shared__ unsigned short Bs[64][40];
    int tid = threadIdx.x;
    int rowBase = blockIdx.y * 64;
    int colBase = blockIdx.x * 64;

    int wave = tid >> 6;
    int l    = tid & 63;
    int wr = wave >> 1, wc = wave & 1;
    int lane16 = l & 15;
    int kb = (l >> 4) * 8;

    int sr = tid >> 2;
    int sk = (tid & 3) << 3;
    const unsigned short* Ap = A + (size_t)(rowBase + sr) * K + sk;
    const unsigned short* Bp = B + (size_t)(colBase + sr) * K + sk;

    f32x4 acc[2][2] = {};

    for (int k0 = 0; k0 < K; k0 += 32) {
        float4 av = *(const float4*)(Ap + k0);
        float4 bv = *(const float4*)(Bp + k0);
        __syncthreads();
        *(float4*)(&As[sr][sk]) = av;
        *(float4*)(&Bs[sr][sk]) = bv;
        __syncthreads();
        bf16x8 a0 = *(const bf16x8*)(&As[wr * 32 + lane16][kb]);
        bf16x8 a1 = *(const bf16x8*)(&As[wr * 32 + 16 + lane16][kb]);
        bf16x8 b0 = *(const bf16x8*)(&Bs[wc * 32 + lane16][kb]);
        bf16x8 b1 = *(const bf16x8*)(&Bs[wc * 32 + 16 + lane16][kb]);
        acc[0][0] = __builtin_amdgcn_mfma_f32_16x16x32_bf16(a0, b0, acc[0][0], 0, 0, 0);
        acc[0][1] = __builtin_amdgcn_mfma_f32_16x16x32_bf16(a0, b1, acc[0][1], 0, 0, 0);
        acc[1][0] = __builtin_amdgcn_mfma_f32_16x16x32_bf16(a1, b0, acc[1][0], 0, 0, 0);
        acc[1][1] = __builtin_amdgcn_mfma_f32_16x16x32_bf16(a1, b1, acc[1][1], 0, 0, 0);
    }

    int crow0 = rowBase + wr * 32 + (l >> 4) * 4;
    int ccol0 = colBase + wc * 32 + lane16;
    float bsv[2];
    #pragma unroll
    for (int j = 0; j < 2; ++j) {
        bsv[j] = bias[ccol0 + j * 16];
        if (BIAS2) bsv[j] += bias2[ccol0 + j * 16];
    }
    #pragma unroll
    for (int i = 0; i < 2; ++i) {
        #pragma unroll
        for (int r = 0; r < 4; ++r) {
            int row = crow0 + i * 16 + r;
            #pragma unroll
            for (int j = 0; j < 2; ++j) {
                float v = acc[i][j][r] + bsv[j];
                if (DO_LRELU) v = lrelu(v);
                size_t off = (size_t)row * N + ccol0 + j * 16;
                if (OUTBF) ((unsigned short*)Cout)[off] = f2bf(v);
                else       ((float*)Cout)[off] = v;
            }
        }
    }
}

// ---------------------------------------------------------------------------
// Split-K bf16 MFMA GEMM: writes f32 partials. (unchanged)
// ---------------------------------------------------------------------------
__global__ void gemm_bf16_splitk_kernel(const unsigned short* __restrict__ A,
                                        const unsigned short* __restrict__ B,
                                        float* __restrict__ part,
                                        int M, int N, int K, int kChunk) {
    __shared__ unsigned short As[64][40];
    __shared__ unsigned short Bs[64][40];
    int tid = threadIdx.x;
    int rowBase = blockIdx.y * 64;
    int colBase = blockIdx.x * 64;
    int s = blockIdx.z;
    int kStart = s * kChunk;
    int kEnd = kStart + kChunk;

    int wave = tid >> 6;
    int l    = tid & 63;
    int wr = wave >> 1, wc = wave & 1;
    int lane16 = l & 15;
    int kb = (l >> 4) * 8;

    int sr = tid >> 2;
    int sk = (tid & 3) << 3;
    const unsigned short* Ap = A + (size_t)(rowBase + sr) * K + sk;
    const unsigned short* Bp = B + (size_t)(colBase + sr) * K + sk;

    f32x4 acc[2][2] = {};

    for (int k0 = kStart; k0 < kEnd; k0 += 32) {
        float4 av = *(const float4*)(Ap + k0);
        float4 bv = *(const float4*)(Bp + k0);
        __syncthreads();
        *(float4*)(&As[sr][sk]) = av;
        *(float4*)(&Bs[sr][sk]) = bv;
        __syncthreads();
        bf16x8 a0 = *(const bf16x8*)(&As[wr * 32 + lane16][kb]);
        bf16x8 a1 = *(const bf16x8*)(&As[wr * 32 + 16 + lane16][kb]);
        bf16x8 b0 = *(const bf16x8*)(&Bs[wc * 32 + lane16][kb]);
        bf16x8 b1 = *(const bf16x8*)(&Bs[wc * 32 + 16 + lane16][kb]);
        acc[0][0] = __builtin_amdgcn_mfma_f32_16x16x32_bf16(a0, b0, acc[0][0], 0, 0, 0);
        acc[0][1] = __builtin_amdgcn_mfma_f32_16x16x32_bf16(a0, b1, acc[0][1], 0, 0, 0);
        acc[1][0] = __builtin_amdgcn_mfma_f32_16x16x32_bf16(a1, b0, acc[1][0], 0, 0, 0);
        acc[1][1] = __builtin_amdgcn_mfma_f32_16x16x32_bf16(a1, b1, acc[1][1], 0, 0, 0);
    }

    float* Cp = part + (size_t)s * M * N;
    int crow0 = rowBase + wr * 32 + (l >> 4) * 4;
    int ccol0 = colBase + wc * 32 + lane16;
    #pragma unroll
    for (int i = 0; i < 2; ++i)
        #pragma unroll
        for (int r = 0; r < 4; ++r) {
            int row = crow0 + i * 16 + r;
            #pragma unroll
            for (int j = 0; j < 2; ++j)
                Cp[(size_t)row * N + ccol0 + j * 16] = acc[i][j][r];
        }
}

// ---------------------------------------------------------------------------
// Split-K reduce. (S=9)
// ---------------------------------------------------------------------------
template<int S>
__global__ void splitk_reduce_kernel(const float* __restrict__ part,
                                     const float* __restrict__ bias,
                                     unsigned short* __restrict__ out,
                                     int MN, int N) {
    int i4 = blockIdx.x * blockDim.x + threadIdx.x;
    if (i4 * 4 >= MN) return;
    float4 acc = ((const float4*)part)[i4];
    #pragma unroll
    for (int s = 1; s < S; ++s) {
        float4 p = ((const float4*)(part + (size_t)s * MN))[i4];
        acc.x += p.x; acc.y += p.y; acc.z += p.z; acc.w += p.w;
    }
    int col4 = i4 % (N / 4);
    float4 bv = ((const float4*)bias)[col4];
    float o0 = lrelu(acc.x + bv.x);
    float o1 = lrelu(acc.y + bv.y);
    float o2 = lrelu(acc.z + bv.z);
    float o3 = lrelu(acc.w + bv.w);
    uint2 p;
    p.x = (unsigned)f2bf(o0) | ((unsigned)f2bf(o1) << 16);
    p.y = (unsigned)f2bf(o2) | ((unsigned)f2bf(o3) << 16);
    ((uint2*)out)[i4] = p;
}

// ---------------------------------------------------------------------------
// LSTM init: HA (bf16) = h0; zero barrier counters.
// ---------------------------------------------------------------------------
__global__ void lstm_init_kernel(const float* __restrict__ h0,
                                 unsigned short* __restrict__ HA,
                                 int* __restrict__ bar) {
    int i = blockIdx.x * blockDim.x + threadIdx.x;
    if (i < 16384) HA[i] = f2bf(h0[i]);
    if (i < 64) bar[i] = 0;
}

// ---------------------------------------------------------------------------
// Persistent LSTM scan — R13/R17-proven counter barrier (244 µs floor).
// ---------------------------------------------------------------------------
__global__ __launch_bounds__(256, 1) void lstm_scan_kernel(
        const unsigned short* __restrict__ whh_b,   // [2048][512] bf16
        const unsigned short* __restrict__ wih_b,   // [2048][512] bf16
        const float* __restrict__ bih,
        const float* __restrict__ bhh,
        const unsigned short* __restrict__ HA,      // [32][512] bf16
        const float* __restrict__ c0,               // [32][512] f32
        const unsigned short* __restrict__ hfc2,    // [2048][512] bf16
        const float* __restrict__ done,             // [2048] f32
        unsigned short* __restrict__ feat,          // [2048][512] bf16
        float* __restrict__ hN, float* __restrict__ cN,
        int* __restrict__ bar) {
    __shared__ float mds[2048];
    __shared__ float Gs[4][16][17];
    __shared__ unsigned short Hs[16][520];
    __shared__ unsigned short Xh[16][520];

    int tid = threadIdx.x;
    int jt = blockIdx.x >> 1;
    int bt = blockIdx.x & 1;

    for (int i = tid; i < 2048; i += 256) mds[i] = 1.0f - done[i];

    int g = tid >> 6;
    int l = tid & 63;
    int lane16 = l & 15;
    int khi = l >> 4;
    const unsigned short* Wp =
        whh_b + ((size_t)g * 512 + jt * 16 + lane16) * 512 + khi * 8;
    const unsigned short* Wxp =
        wih_b + ((size_t)g * 512 + jt * 16 + lane16) * 512 + khi * 8;
    bf16x8 wreg[16], wxreg[16];
    #pragma unroll
    for (int kk = 0; kk < 16; ++kk) {
        wreg[kk]  = *(const bf16x8*)(Wp + kk * 32);
        wxreg[kk] = *(const bf16x8*)(Wxp + kk * 32);
    }

    int jloc = tid & 15;
    int bloc = tid >> 4;
    int j = jt * 16 + jloc;
    int b = bt * 16 + bloc;
    float c_reg = c0[b * 512 + j];
    float bsv[4];
    #pragma unroll
    for (int gg = 0; gg < 4; ++gg)
        bsv[gg] = bih[gg * 512 + j] + bhh[gg * 512 + j];

    int* mybar = bar + bt * 32;

    {
        const float4* h4 = (const float4*)(HA + bt * 8192);
        const float4* x4 = (const float4*)(hfc2 + bt * 8192);
        #pragma unroll
        for (int u0 = 0; u0 < 4; ++u0) {
            int u = tid + u0 * 256;
            float4 hv = h4[u];
            float4 xv = x4[u];
            *(float4*)&Hs[u >> 6][(u & 63) * 8] = hv;
            *(float4*)&Xh[u >> 6][(u & 63) * 8] = xv;
        }
    }
    __syncthreads();

    for (int t = 0; t < 64; ++t) {
        f32x4 hacc0 = {}, hacc1 = {}, xacc0 = {}, xacc1 = {};
        #pragma unroll
        for (int kk = 0; kk < 16; kk += 2) {
            bf16x8 hb0 = *(const bf16x8*)(&Hs[lane16][khi * 8 + kk * 32]);
            bf16x8 hb1 = *(const bf16x8*)(&Hs[lane16][khi * 8 + kk * 32 + 32]);
            bf16x8 xb0 = *(const bf16x8*)(&Xh[lane16][khi * 8 + kk * 32]);
            bf16x8 xb1 = *(const bf16x8*)(&Xh[lane16][khi * 8 + kk * 32 + 32]);
            hacc0 = __builtin_amdgcn_mfma_f32_16x16x32_bf16(wreg[kk],      hb0, hacc0, 0, 0, 0);
            hacc1 = __builtin_amdgcn_mfma_f32_16x16x32_bf16(wreg[kk + 1],  hb1, hacc1, 0, 0, 0);
            xacc0 = __builtin_amdgcn_mfma_f32_16x16x32_bf16(wxreg[kk],     xb0, xacc0, 0, 0, 0);
            xacc1 = __builtin_amdgcn_mfma_f32_16x16x32_bf16(wxreg[kk + 1], xb1, xacc1, 0, 0, 0);
        }
        f32x4 hacc = hacc0 + hacc1;
        f32x4 xacc = xacc0 + xacc1;
        float mcol = mds[t * 32 + bt * 16 + lane16];
        #pragma unroll
        for (int r = 0; r < 4; ++r)
            Gs[g][khi * 4 + r][lane16] = xacc[r] + mcol * hacc[r];
        __syncthreads();

        float4 xv0, xv1, xv2, xv3;
        if (t < 63) {
            const float4* x4 =
                (const float4*)(hfc2 + (size_t)(t + 1) * 16384 + bt * 8192);
            xv0 = x4[tid];
            xv1 = x4[tid + 256];
            xv2 = x4[tid + 512];
            xv3 = x4[tid + 768];
        }

        int row = t * 32 + b;
        float m = mds[row];
        float ai = bsv[0] + Gs[0][jloc][bloc];
        float af = bsv[1] + Gs[1][jloc][bloc];
        float ag = bsv[2] + Gs[2][jloc][bloc];
        float ao = bsv[3] + Gs[3][jloc][bloc];
        float cp = c_reg * m;
        float si = 1.f / (1.f + __expf(-ai));
        float sf = 1.f / (1.f + __expf(-af));
        float so = 1.f / (1.f + __expf(-ao));
        c_reg = sf * cp + si * tanhf(ag);
        float hn = so * tanhf(c_reg);
        feat[(size_t)row * 512 + j] = f2bf(hn);
        if (t == 63) {
            hN[b * 512 + j] = hn;
            cN[b * 512 + j] = c_reg;
        }

        if (t < 63) {
            *(float4*)&Xh[tid >> 6][(tid & 63) * 8] = xv0;
            {
                int u = tid + 256;
                *(float4*)&Xh[u >> 6][(u & 63) * 8] = xv1;
                u = tid + 512;
                *(float4*)&Xh[u >> 6][(u & 63) * 8] = xv2;
                u = tid + 768;
                *(float4*)&Xh[u >> 6][(u & 63) * 8] = xv3;
            }
            __syncthreads();
            if (tid == 0) {
                int target = (t + 1) * 32;
                __hip_atomic_fetch_add(mybar, 1, __ATOMIC_ACQ_REL,
                                       __HIP_MEMORY_SCOPE_AGENT);
                while (__hip_atomic_load(mybar, __ATOMIC_RELAXED,
                                         __HIP_MEMORY_SCOPE_AGENT) < target)
                    __builtin_amdgcn_s_sleep(2);
                __builtin_amdgcn_fence(__ATOMIC_ACQUIRE, "agent");
            }
            __syncthreads();
            const float4* h4 =
                (const float4*)(feat + (size_t)t * 16384 + bt * 8192);
            #pragma unroll
            for (int u0 = 0; u0 < 4; ++u0) {
                int u = tid + u0 * 256;
                float4 hv = h4[u];
                *(float4*)&Hs[u >> 6][(u & 63) * 8] = hv;
            }
            __syncthreads();
        }
    }
}

// ---------------------------------------------------------------------------
extern "C" void kernel_launch(void* const* d_in, const int* in_sizes, int n_in,
                              void* d_out, int out_size, void* d_ws, size_t ws_size,
                              hipStream_t stream) {
    const float* x    = (const float*)d_in[0];
    const float* done = (const float*)d_in[1];
    const float* h0   = (const float*)d_in[2];
    const float* c0   = (const float*)d_in[3];
    const float* c1w  = (const float*)d_in[4];
    const float* c1b  = (const float*)d_in[5];
    const float* c2w  = (const float*)d_in[6];
    const float* c2b  = (const float*)d_in[7];
    const float* c3w  = (const float*)d_in[8];
    const float* c3b  = (const float*)d_in[9];
    const float* fc1w = (const float*)d_in[10];
    const float* fc1b = (const float*)d_in[11];
    const float* fc2w = (const float*)d_in[12];
    const float* fc2b = (const float*)d_in[13];
    const float* wih  = (const float*)d_in[14];
    const float* whh  = (const float*)d_in[15];
    const float* bih  = (const float*)d_in[16];
    const float* bhh  = (const float*)d_in[17];
    const float* dfw  = (const float*)d_in[18];
    const float* dfb  = (const float*)d_in[19];
    const float* dw   = (const float*)d_in[20];
    const float* db   = (const float*)d_in[21];
    float* out = (float*)d_out;

    const size_t CONV_ELEMS = 57802752;            // 2048*4*84*84
    char* S = (char*)d_ws;
    unsigned short* c1out  = (unsigned short*)S;   S += CONV_ELEMS * 2;
    unsigned short* c2out  = (unsigned short*)S;   S += CONV_ELEMS * 2;
    unsigned short* c3out  = (unsigned short*)S;   S += CONV_ELEMS * 2;
    // contiguous weight region (cvt_all writes it as one flat array)
    unsigned short* fc1w_b = (unsigned short*)S;   S += 28901376;
    unsigned short* fc2w_b = (unsigned short*)S;   S += 524288;
    unsigned short* wih_b  = (unsigned short*)S;   S += 2097152;
    unsigned short* whh_b  = (unsigned short*)S;   S += 2097152;
    unsigned short* dfw_b  = (unsigned short*)S;   S += 131072;
    unsigned short* dw_b   = (unsigned short*)S;   S += 16384;
    unsigned short* hfc1_b = (unsigned short*)S;   S += 2097152;
    unsigned short* hfc2_b = (unsigned short*)S;   S += 2097152;
    unsigned short* feat_b = (unsigned short*)S;   S += 2097152;
    unsigned short* dfeat_b= (unsigned short*)S;   S += 524288;
    unsigned short* HA     = (unsigned short*)S;   S += 32768;
    float*          part   = (float*)S;            S += 37748736;  // 9x[2048][512] f32
    int*            bar    = (int*)S;              S += 256;

    // --- conv stack (R17-proven: 3 separate LDS-tiled kernels) ---
    dim3 cgrid(2048, 7);
    conv_tile_kernel<5, false, true><<<cgrid, 256, 0, stream>>>(x,     c1w, c1b, c1out);
    conv_tile_kernel<3, true,  true><<<cgrid, 256, 0, stream>>>(c1out, c2w, c2b, c2out);
    conv_tile_kernel<3, true,  true><<<cgrid, 256, 0, stream>>>(c2out, c3w, c3b, c3out);

    // --- all weight conversions in one kernel (dst region contiguous) ---
    cvt_all_kernel<<<dim3((4220928 + 255) / 256), 256, 0, stream>>>(
        fc1w, fc2w, wih, whh, dfw, dw, fc1w_b);

    // --- fc1: split-K x9, then reduce+bias+lrelu ---
    gemm_bf16_splitk_kernel<<<dim3(8, 32, 9), 256, 0, stream>>>(
        c3out, fc1w_b, part, 2048, 512, 28224, 3136);
    splitk_reduce_kernel<9><<<dim3(1024), 256, 0, stream>>>(
        part, fc1b, hfc1_b, 1048576, 512);

    // --- fc2 ---
    gemm_bf16_kernel<true, false, true><<<dim3(8, 32), 256, 0, stream>>>(
        hfc1_b, fc2w_b, fc2b, nullptr, hfc2_b, 2048, 512, 512);

    // --- LSTM scan (single persistent launch; R13 barrier) ---
    lstm_init_kernel<<<dim3(64), 256, 0, stream>>>(h0, HA, bar);
    lstm_scan_kernel<<<dim3(64), 256, 0, stream>>>(
        whh_b, wih_b, bih, bhh, HA, c0, hfc2_b, done, feat_b,
        out + 131072, out + 131072 + 16384, bar);

    // --- discriminator head ---
    gemm_bf16_kernel<true, false, true><<<dim3(2, 32), 256, 0, stream>>>(
        feat_b, dfw_b, dfb, nullptr, dfeat_b, 2048, 128, 512);
    gemm_bf16_kernel<false, false, false><<<dim3(1, 32), 256, 0, stream>>>(
        dfeat_b, dw_b, db, nullptr, out, 2048, 64, 128);
}

// Round 20
// 819.315 us; speedup vs baseline: 1.2798x; 1.0090x over previous
//
#include <hip/hip_runtime.h>
#include <math.h>

#define SLOPE 0.01f

typedef __attribute__((ext_vector_type(8))) short bf16x8;
typedef __attribute__((ext_vector_type(4))) float f32x4;
typedef unsigned short ushort_t;

__device__ __forceinline__ float lrelu(float x) {
    return x > 0.f ? x : SLOPE * x;
}

__device__ __forceinline__ unsigned short f2bf(float f) {
    unsigned int u = __float_as_uint(f);
    u += 0x7fffu + ((u >> 16) & 1u);
    return (unsigned short)(u >> 16);
}

__device__ __forceinline__ float bf2f(unsigned short u) {
    return __uint_as_float((unsigned int)u << 16);
}

// ---------------------------------------------------------------------------
// Merged f32 -> bf16 conversion for ALL weights (dst buffers contiguous).
// ---------------------------------------------------------------------------
__global__ void cvt_all_kernel(const float* __restrict__ s0,
                               const float* __restrict__ s1,
                               const float* __restrict__ s2,
                               const float* __restrict__ s3,
                               const float* __restrict__ s4,
                               const float* __restrict__ s5,
                               unsigned short* __restrict__ dst) {
    int i = blockIdx.x * blockDim.x + threadIdx.x;
    if (i >= 4220928) return;
    const float* src; int base;
    if (i < 3612672)      { src = s0; base = 0; }
    else if (i < 3678208) { src = s1; base = 3612672; }
    else if (i < 3940352) { src = s2; base = 3678208; }
    else if (i < 4202496) { src = s3; base = 3940352; }
    else if (i < 4218880) { src = s4; base = 4202496; }
    else                  { src = s5; base = 4218880; }
    float4 v = ((const float4*)src)[i - base];
    uint2 o;
    o.x = (unsigned)f2bf(v.x) | ((unsigned)f2bf(v.y) << 16);
    o.y = (unsigned)f2bf(v.z) | ((unsigned)f2bf(v.w) << 16);
    ((uint2*)dst)[i] = o;
}

// ---------------------------------------------------------------------------
// LDS-tiled conv 4->4, SAME, kernel K, fused bias+LeakyReLU. (R17-proven)
// ---------------------------------------------------------------------------
template<int K, bool INBF, bool OUTBF>
__global__ __launch_bounds__(256) void conv_tile_kernel(
        const void* __restrict__ in_v,
        const float* __restrict__ w,
        const float* __restrict__ b,
        void* __restrict__ out_v) {
    constexpr int HALO = K / 2;
    constexpr int TILE_H = 12;
    constexpr int SH = TILE_H + 2 * HALO;
    constexpr int SW = 88;
    __shared__ float smem[4][SH][SW];

    int tid = threadIdx.x;
    int n = blockIdx.x;
    int row0 = blockIdx.y * TILE_H;
    const size_t imgOff = (size_t)n * (4 * 84 * 84);

    for (int it = tid; it < 4 * SH * 22; it += 256) {
        int item = it % 22;
        int rr = it / 22;
        int r = rr % SH;
        int ci = rr / SH;
        int gr = row0 + r - HALO;
        bool rv = (unsigned)gr < 84u;
        if (item < 21) {
            int gc = item * 4;
            float4 v = make_float4(0.f, 0.f, 0.f, 0.f);
            if (rv) {
                size_t off = imgOff + ((size_t)ci * 84 + gr) * 84 + gc;
                if (INBF) {
                    unsigned long long u =
                        *(const unsigned long long*)((const ushort_t*)in_v + off);
                    v.x = bf2f((unsigned short)u);
                    v.y = bf2f((unsigned short)(u >> 16));
                    v.z = bf2f((unsigned short)(u >> 32));
                    v.w = bf2f((unsigned short)(u >> 48));
                } else {
                    v = *(const float4*)((const float*)in_v + off);
                }
            }
            smem[ci][r][HALO + gc + 0] = v.x;
            smem[ci][r][HALO + gc + 1] = v.y;
            smem[ci][r][HALO + gc + 2] = v.z;
            smem[ci][r][HALO + gc + 3] = v.w;
        } else {
            if (HALO == 2) {
                smem[ci][r][0] = 0.f; smem[ci][r][1] = 0.f;
                smem[ci][r][86] = 0.f; smem[ci][r][87] = 0.f;
            } else {
                smem[ci][r][0] = 0.f;
                smem[ci][r][85] = 0.f; smem[ci][r][86] = 0.f; smem[ci][r][87] = 0.f;
            }
        }
    }
    __syncthreads();

    if (tid >= 252) return;
    int r  = tid / 21;
    int w0 = (tid % 21) * 4;

    float acc[4][4];
    #pragma unroll
    for (int co = 0; co < 4; ++co) {
        float bv = b[co];
        #pragma unroll
        for (int dw = 0; dw < 4; ++dw) acc[co][dw] = bv;
    }

    #pragma unroll
    for (int ci = 0; ci < 4; ++ci) {
        #pragma unroll
        for (int kh = 0; kh < K; ++kh) {
            float vals[K + 3];
            float4 v0 = *(const float4*)&smem[ci][r + kh][w0];
            vals[0] = v0.x; vals[1] = v0.y; vals[2] = v0.z; vals[3] = v0.w;
            if (K == 5) {
                float4 v1 = *(const float4*)&smem[ci][r + kh][w0 + 4];
                vals[4] = v1.x; vals[5] = v1.y; vals[6] = v1.z; vals[7] = v1.w;
            } else {
                float2 v1 = *(const float2*)&smem[ci][r + kh][w0 + 4];
                vals[4] = v1.x; vals[5] = v1.y;
            }
            #pragma unroll
            for (int co = 0; co < 4; ++co) {
                #pragma unroll
                for (int kw = 0; kw < K; ++kw) {
                    float wv = w[((co * 4 + ci) * K + kh) * K + kw];
                    #pragma unroll
                    for (int dw = 0; dw < 4; ++dw)
                        acc[co][dw] += vals[kw + dw] * wv;
                }
            }
        }
    }

    int oh = row0 + r;
    #pragma unroll
    for (int co = 0; co < 4; ++co) {
        size_t off = imgOff + ((size_t)co * 84 + oh) * 84 + w0;
        float o0 = lrelu(acc[co][0]);
        float o1 = lrelu(acc[co][1]);
        float o2 = lrelu(acc[co][2]);
        float o3 = lrelu(acc[co][3]);
        if (OUTBF) {
            uint2 p;
            p.x = (unsigned)f2bf(o0) | ((unsigned)f2bf(o1) << 16);
            p.y = (unsigned)f2bf(o2) | ((unsigned)f2bf(o3) << 16);
            *(uint2*)((ushort_t*)out_v + off) = p;
        } else {
            *(float4*)((float*)out_v + off) = make_float4(o0, o1, o2, o3);
        }
    }
}

// ---------------------------------------------------------------------------
// bf16 MFMA GEMM (NT) with epilogue (fc2, heads). (unchanged)
// ---------------------------------------------------------------------------
template<bool DO_LRELU, bool BIAS2, bool OUTBF>
__global__ void gemm_bf16_kernel(const unsigned short* __restrict__ A,
                                 const unsigned short* __restrict__ B,
                                 const float* __restrict__ bias,
                                 const float* __restrict__ bias2,
                                 void* __restrict__ Cout,
                                 int M, int N, int K) {
    __shared__ unsigned short As[64][40];
    __shared__ unsigned short Bs[64][40];
    int tid = threadIdx.x;
    int rowBase = blockIdx.y * 64;
    int colBase = blockIdx.x * 64;

    int wave = tid >> 6;
    int l    = tid & 63;
    int wr = wave >> 1, wc = wave & 1;
    int lane16 = l & 15;
    int kb = (l >> 4) * 8;

    int sr = tid >> 2;
    int sk = (tid & 3) << 3;
    const unsigned short* Ap = A + (size_t)(rowBase + sr) * K + sk;
    const unsigned short* Bp = B + (size_t)(colBase + sr) * K + sk;

    f32x4 acc[2][2] = {};

    for (int k0 = 0; k0 < K; k0 += 32) {
        float4 av = *(const float4*)(Ap + k0);
        float4 bv = *(const float4*)(Bp + k0);
        __syncthreads();
        *(float4*)(&As[sr][sk]) = av;
        *(float4*)(&Bs[sr][sk]) = bv;
        __syncthreads();
        bf16x8 a0 = *(const bf16x8*)(&As[wr * 32 + lane16][kb]);
        bf16x8 a1 = *(const bf16x8*)(&As[wr * 32 + 16 + lane16][kb]);
        bf16x8 b0 = *(const bf16x8*)(&Bs[wc * 32 + lane16][kb]);
        bf16x8 b1 = *(const bf16x8*)(&Bs[wc * 32 + 16 + lane16][kb]);
        acc[0][0] = __builtin_amdgcn_mfma_f32_16x16x32_bf16(a0, b0, acc[0][0], 0, 0, 0);
        acc[0][1] = __builtin_amdgcn_mfma_f32_16x16x32_bf16(a0, b1, acc[0][1], 0, 0, 0);
        acc[1][0] = __builtin_amdgcn_mfma_f32_16x16x32_bf16(a1, b0, acc[1][0], 0, 0, 0);
        acc[1][1] = __builtin_amdgcn_mfma_f32_16x16x32_bf16(a1, b1, acc[1][1], 0, 0, 0);
    }

    int crow0 = rowBase + wr * 32 + (l >> 4) * 4;
    int ccol0 = colBase + wc * 32 + lane16;
    float bsv[2];
    #pragma unroll
    for (int j = 0; j < 2; ++j) {
        bsv[j] = bias[ccol0 + j * 16];
        if (BIAS2) bsv[j] += bias2[ccol0 + j * 16];
    }
    #pragma unroll
    for (int i = 0; i < 2; ++i) {
        #pragma unroll
        for (int r = 0; r < 4; ++r) {
            int row = crow0 + i * 16 + r;
            #pragma unroll
            for (int j = 0; j < 2; ++j) {
                float v = acc[i][j][r] + bsv[j];
                if (DO_LRELU) v = lrelu(v);
                size_t off = (size_t)row * N + ccol0 + j * 16;
                if (OUTBF) ((unsigned short*)Cout)[off] = f2bf(v);
                else       ((float*)Cout)[off] = v;
            }
        }
    }
}

// ---------------------------------------------------------------------------
// Split-K bf16 MFMA GEMM, BM=128 x BN=64 (fc1 only): 4 waves, each a 64x32
// sub-tile (4x2 frags of 16x16x32) -> 8 MFMAs per 6 ds_reads per K-step,
// half the barrier crossings / B-traffic per FLOP vs the 64x64 tile.
// Writes f32 partials; reduce unchanged.
// ---------------------------------------------------------------------------
__global__ void gemm_bf16_splitk128_kernel(const unsigned short* __restrict__ A,
                                           const unsigned short* __restrict__ B,
                                           float* __restrict__ part,
                                           int M, int N, int K, int kChunk) {
    __shared__ unsigned short As[128][40];
    __shared__ unsigned short Bs[64][40];
    int tid = threadIdx.x;
    int rowBase = blockIdx.y * 128;
    int colBase = blockIdx.x * 64;
    int s = blockIdx.z;
    int kStart = s * kChunk;
    int kEnd = kStart + kChunk;

    int wave = tid >> 6;
    int l    = tid & 63;
    int wr = wave >> 1, wc = wave & 1;   // wave tile: rows wr*64.., cols wc*32..
    int lane16 = l & 15;
    int kb = (l >> 4) * 8;

    int sr = tid >> 2;            // 0..63
    int sk = (tid & 3) << 3;      // 0,8,16,24
    const unsigned short* Ap0 = A + (size_t)(rowBase + sr) * K + sk;
    const unsigned short* Ap1 = Ap0 + (size_t)64 * K;
    const unsigned short* Bp  = B + (size_t)(colBase + sr) * K + sk;

    f32x4 acc[4][2] = {};

    for (int k0 = kStart; k0 < kEnd; k0 += 32) {
        float4 av0 = *(const float4*)(Ap0 + k0);
        float4 av1 = *(const float4*)(Ap1 + k0);
        float4 bv  = *(const float4*)(Bp + k0);
        __syncthreads();
        *(float4*)(&As[sr][sk])      = av0;
        *(float4*)(&As[64 + sr][sk]) = av1;
        *(float4*)(&Bs[sr][sk])      = bv;
        __syncthreads();
        bf16x8 a0 = *(const bf16x8*)(&As[wr * 64 +  0 + lane16][kb]);
        bf16x8 a1 = *(const bf16x8*)(&As[wr * 64 + 16 + lane16][kb]);
        bf16x8 a2 = *(const bf16x8*)(&As[wr * 64 + 32 + lane16][kb]);
        bf16x8 a3 = *(const bf16x8*)(&As[wr * 64 + 48 + lane16][kb]);
        bf16x8 b0 = *(const bf16x8*)(&Bs[wc * 32 +  0 + lane16][kb]);
        bf16x8 b1 = *(const bf16x8*)(&Bs[wc * 32 + 16 + lane16][kb]);
        acc[0][0] = __builtin_amdgcn_mfma_f32_16x16x32_bf16(a0, b0, acc[0][0], 0, 0, 0);
        acc[0][1] = __builtin_amdgcn_mfma_f32_16x16x32_bf16(a0, b1, acc[0][1], 0, 0, 0);
        acc[1][0] = __builtin_amdgcn_mfma_f32_16x16x32_bf16(a1, b0, acc[1][0], 0, 0, 0);
        acc[1][1] = __builtin_amdgcn_mfma_f32_16x16x32_bf16(a1, b1, acc[1][1], 0, 0, 0);
        acc[2][0] = __builtin_amdgcn_mfma_f32_16x16x32_bf16(a2, b0, acc[2][0], 0, 0, 0);
        acc[2][1] = __builtin_amdgcn_mfma_f32_16x16x32_bf16(a2, b1, acc[2][1], 0, 0, 0);
        acc[3][0] = __builtin_amdgcn_mfma_f32_16x16x32_bf16(a3, b0, acc[3][0], 0, 0, 0);
        acc[3][1] = __builtin_amdgcn_mfma_f32_16x16x32_bf16(a3, b1, acc[3][1], 0, 0, 0);
    }

    float* Cp = part + (size_t)s * M * N;
    int crow0 = rowBase + wr * 64 + (l >> 4) * 4;
    int ccol0 = colBase + wc * 32 + lane16;
    #pragma unroll
    for (int i = 0; i < 4; ++i)
        #pragma unroll
        for (int r = 0; r < 4; ++r) {
            int row = crow0 + i * 16 + r;
            #pragma unroll
            for (int j = 0; j < 2; ++j)
                Cp[(size_t)row * N + ccol0 + j * 16] = acc[i][j][r];
        }
}

// ---------------------------------------------------------------------------
// Split-K reduce. (S=9)
// ---------------------------------------------------------------------------
template<int S>
__global__ void splitk_reduce_kernel(const float* __restrict__ part,
                                     const float* __restrict__ bias,
                                     unsigned short* __restrict__ out,
                                     int MN, int N) {
    int i4 = blockIdx.x * blockDim.x + threadIdx.x;
    if (i4 * 4 >= MN) return;
    float4 acc = ((const float4*)part)[i4];
    #pragma unroll
    for (int s = 1; s < S; ++s) {
        float4 p = ((const float4*)(part + (size_t)s * MN))[i4];
        acc.x += p.x; acc.y += p.y; acc.z += p.z; acc.w += p.w;
    }
    int col4 = i4 % (N / 4);
    float4 bv = ((const float4*)bias)[col4];
    float o0 = lrelu(acc.x + bv.x);
    float o1 = lrelu(acc.y + bv.y);
    float o2 = lrelu(acc.z + bv.z);
    float o3 = lrelu(acc.w + bv.w);
    uint2 p;
    p.x = (unsigned)f2bf(o0) | ((unsigned)f2bf(o1) << 16);
    p.y = (unsigned)f2bf(o2) | ((unsigned)f2bf(o3) << 16);
    ((uint2*)out)[i4] = p;
}

// ---------------------------------------------------------------------------
// LSTM init: HA (bf16) = h0; zero barrier counters.
// ---------------------------------------------------------------------------
__global__ void lstm_init_kernel(const float* __restrict__ h0,
                                 unsigned short* __restrict__ HA,
                                 int* __restrict__ bar) {
    int i = blockIdx.x * blockDim.x + threadIdx.x;
    if (i < 16384) HA[i] = f2bf(h0[i]);
    if (i < 64) bar[i] = 0;
}

// ---------------------------------------------------------------------------
// Persistent LSTM scan — R13/R17-proven counter barrier (243 µs floor).
// ---------------------------------------------------------------------------
__global__ __launch_bounds__(256, 1) void lstm_scan_kernel(
        const unsigned short* __restrict__ whh_b,   // [2048][512] bf16
        const unsigned short* __restrict__ wih_b,   // [2048][512] bf16
        const float* __restrict__ bih,
        const float* __restrict__ bhh,
        const unsigned short* __restrict__ HA,      // [32][512] bf16
        const float* __restrict__ c0,               // [32][512] f32
        const unsigned short* __restrict__ hfc2,    // [2048][512] bf16
        const float* __restrict__ done,             // [2048] f32
        unsigned short* __restrict__ feat,          // [2048][512] bf16
        float* __restrict__ hN, float* __restrict__ cN,
        int* __restrict__ bar) {
    __shared__ float mds[2048];
    __shared__ float Gs[4][16][17];
    __shared__ unsigned short Hs[16][520];
    __shared__ unsigned short Xh[16][520];

    int tid = threadIdx.x;
    int jt = blockIdx.x >> 1;
    int bt = blockIdx.x & 1;

    for (int i = tid; i < 2048; i += 256) mds[i] = 1.0f - done[i];

    int g = tid >> 6;
    int l = tid & 63;
    int lane16 = l & 15;
    int khi = l >> 4;
    const unsigned short* Wp =
        whh_b + ((size_t)g * 512 + jt * 16 + lane16) * 512 + khi * 8;
    const unsigned short* Wxp =
        wih_b + ((size_t)g * 512 + jt * 16 + lane16) * 512 + khi * 8;
    bf16x8 wreg[16], wxreg[16];
    #pragma unroll
    for (int kk = 0; kk < 16; ++kk) {
        wreg[kk]  = *(const bf16x8*)(Wp + kk * 32);
        wxreg[kk] = *(const bf16x8*)(Wxp + kk * 32);
    }

    int jloc = tid & 15;
    int bloc = tid >> 4;
    int j = jt * 16 + jloc;
    int b = bt * 16 + bloc;
    float c_reg = c0[b * 512 + j];
    float bsv[4];
    #pragma unroll
    for (int gg = 0; gg < 4; ++gg)
        bsv[gg] = bih[gg * 512 + j] + bhh[gg * 512 + j];

    int* mybar = bar + bt * 32;

    {
        const float4* h4 = (const float4*)(HA + bt * 8192);
        const float4* x4 = (const float4*)(hfc2 + bt * 8192);
        #pragma unroll
        for (int u0 = 0; u0 < 4; ++u0) {
            int u = tid + u0 * 256;
            float4 hv = h4[u];
            float4 xv = x4[u];
            *(float4*)&Hs[u >> 6][(u & 63) * 8] = hv;
            *(float4*)&Xh[u >> 6][(u & 63) * 8] = xv;
        }
    }
    __syncthreads();

    for (int t = 0; t < 64; ++t) {
        f32x4 hacc0 = {}, hacc1 = {}, xacc0 = {}, xacc1 = {};
        #pragma unroll
        for (int kk = 0; kk < 16; kk += 2) {
            bf16x8 hb0 = *(const bf16x8*)(&Hs[lane16][khi * 8 + kk * 32]);
            bf16x8 hb1 = *(const bf16x8*)(&Hs[lane16][khi * 8 + kk * 32 + 32]);
            bf16x8 xb0 = *(const bf16x8*)(&Xh[lane16][khi * 8 + kk * 32]);
            bf16x8 xb1 = *(const bf16x8*)(&Xh[lane16][khi * 8 + kk * 32 + 32]);
            hacc0 = __builtin_amdgcn_mfma_f32_16x16x32_bf16(wreg[kk],      hb0, hacc0, 0, 0, 0);
            hacc1 = __builtin_amdgcn_mfma_f32_16x16x32_bf16(wreg[kk + 1],  hb1, hacc1, 0, 0, 0);
            xacc0 = __builtin_amdgcn_mfma_f32_16x16x32_bf16(wxreg[kk],     xb0, xacc0, 0, 0, 0);
            xacc1 = __builtin_amdgcn_mfma_f32_16x16x32_bf16(wxreg[kk + 1], xb1, xacc1, 0, 0, 0);
        }
        f32x4 hacc = hacc0 + hacc1;
        f32x4 xacc = xacc0 + xacc1;
        float mcol = mds[t * 32 + bt * 16 + lane16];
        #pragma unroll
        for (int r = 0; r < 4; ++r)
            Gs[g][khi * 4 + r][lane16] = xacc[r] + mcol * hacc[r];
        __syncthreads();

        float4 xv0, xv1, xv2, xv3;
        if (t < 63) {
            const float4* x4 =
                (const float4*)(hfc2 + (size_t)(t + 1) * 16384 + bt * 8192);
            xv0 = x4[tid];
            xv1 = x4[tid + 256];
            xv2 = x4[tid + 512];
            xv3 = x4[tid + 768];
        }

        int row = t * 32 + b;
        float m = mds[row];
        float ai = bsv[0] + Gs[0][jloc][bloc];
        float af = bsv[1] + Gs[1][jloc][bloc];
        float ag = bsv[2] + Gs[2][jloc][bloc];
        float ao = bsv[3] + Gs[3][jloc][bloc];
        float cp = c_reg * m;
        float si = 1.f / (1.f + __expf(-ai));
        float sf = 1.f / (1.f + __expf(-af));
        float so = 1.f / (1.f + __expf(-ao));
        c_reg = sf * cp + si * tanhf(ag);
        float hn = so * tanhf(c_reg);
        feat[(size_t)row * 512 + j] = f2bf(hn);
        if (t == 63) {
            hN[b * 512 + j] = hn;
            cN[b * 512 + j] = c_reg;
        }

        if (t < 63) {
            *(float4*)&Xh[tid >> 6][(tid & 63) * 8] = xv0;
            {
                int u = tid + 256;
                *(float4*)&Xh[u >> 6][(u & 63) * 8] = xv1;
                u = tid + 512;
                *(float4*)&Xh[u >> 6][(u & 63) * 8] = xv2;
                u = tid + 768;
                *(float4*)&Xh[u >> 6][(u & 63) * 8] = xv3;
            }
            __syncthreads();
            if (tid == 0) {
                int target = (t + 1) * 32;
                __hip_atomic_fetch_add(mybar, 1, __ATOMIC_ACQ_REL,
                                       __HIP_MEMORY_SCOPE_AGENT);
                while (__hip_atomic_load(mybar, __ATOMIC_RELAXED,
                                         __HIP_MEMORY_SCOPE_AGENT) < target)
                    __builtin_amdgcn_s_sleep(2);
                __builtin_amdgcn_fence(__ATOMIC_ACQUIRE, "agent");
            }
            __syncthreads();
            const float4* h4 =
                (const float4*)(feat + (size_t)t * 16384 + bt * 8192);
            #pragma unroll
            for (int u0 = 0; u0 < 4; ++u0) {
                int u = tid + u0 * 256;
                float4 hv = h4[u];
                *(float4*)&Hs[u >> 6][(u & 63) * 8] = hv;
            }
            __syncthreads();
        }
    }
}

// ---------------------------------------------------------------------------
extern "C" void kernel_launch(void* const* d_in, const int* in_sizes, int n_in,
                              void* d_out, int out_size, void* d_ws, size_t ws_size,
                              hipStream_t stream) {
    const float* x    = (const float*)d_in[0];
    const float* done = (const float*)d_in[1];
    const float* h0   = (const float*)d_in[2];
    const float* c0   = (const float*)d_in[3];
    const float* c1w  = (const float*)d_in[4];
    const float* c1b  = (const float*)d_in[5];
    const float* c2w  = (const float*)d_in[6];
    const float* c2b  = (const float*)d_in[7];
    const float* c3w  = (const float*)d_in[8];
    const float* c3b  = (const float*)d_in[9];
    const float* fc1w = (const float*)d_in[10];
    const float* fc1b = (const float*)d_in[11];
    const float* fc2w = (const float*)d_in[12];
    const float* fc2b = (const float*)d_in[13];
    const float* wih  = (const float*)d_in[14];
    const float* whh  = (const float*)d_in[15];
    const float* bih  = (const float*)d_in[16];
    const float* bhh  = (const float*)d_in[17];
    const float* dfw  = (const float*)d_in[18];
    const float* dfb  = (const float*)d_in[19];
    const float* dw   = (const float*)d_in[20];
    const float* db   = (const float*)d_in[21];
    float* out = (float*)d_out;

    const size_t CONV_ELEMS = 57802752;            // 2048*4*84*84
    char* S = (char*)d_ws;
    unsigned short* c1out  = (unsigned short*)S;   S += CONV_ELEMS * 2;
    unsigned short* c2out  = (unsigned short*)S;   S += CONV_ELEMS * 2;
    unsigned short* c3out  = (unsigned short*)S;   S += CONV_ELEMS * 2;
    unsigned short* fc1w_b = (unsigned short*)S;   S += 28901376;
    unsigned short* fc2w_b = (unsigned short*)S;   S += 524288;
    unsigned short* wih_b  = (unsigned short*)S;   S += 2097152;
    unsigned short* whh_b  = (unsigned short*)S;   S += 2097152;
    unsigned short* dfw_b  = (unsigned short*)S;   S += 131072;
    unsigned short* dw_b   = (unsigned short*)S;   S += 16384;
    unsigned short* hfc1_b = (unsigned short*)S;   S += 2097152;
    unsigned short* hfc2_b = (unsigned short*)S;   S += 2097152;
    unsigned short* feat_b = (unsigned short*)S;   S += 2097152;
    unsigned short* dfeat_b= (unsigned short*)S;   S += 524288;
    unsigned short* HA     = (unsigned short*)S;   S += 32768;
    float*          part   = (float*)S;            S += 37748736;  // 9x[2048][512] f32
    int*            bar    = (int*)S;              S += 256;

    // --- conv stack (R17-proven) ---
    dim3 cgrid(2048, 7);
    conv_tile_kernel<5, false, true><<<cgrid, 256, 0, stream>>>(x,     c1w, c1b, c1out);
    conv_tile_kernel<3, true,  true><<<cgrid, 256, 0, stream>>>(c1out, c2w, c2b, c2out);
    conv_tile_kernel<3, true,  true><<<cgrid, 256, 0, stream>>>(c2out, c3w, c3b, c3out);

    // --- all weight conversions in one kernel ---
    cvt_all_kernel<<<dim3((4220928 + 255) / 256), 256, 0, stream>>>(
        fc1w, fc2w, wih, whh, dfw, dw, fc1w_b);

    // --- fc1: split-K x9 with 128x64 tile, then reduce+bias+lrelu ---
    gemm_bf16_splitk128_kernel<<<dim3(8, 16, 9), 256, 0, stream>>>(
        c3out, fc1w_b, part, 2048, 512, 28224, 3136);
    splitk_reduce_kernel<9><<<dim3(1024), 256, 0, stream>>>(
        part, fc1b, hfc1_b, 1048576, 512);

    // --- fc2 ---
    gemm_bf16_kernel<true, false, true><<<dim3(8, 32), 256, 0, stream>>>(
        hfc1_b, fc2w_b, fc2b, nullptr, hfc2_b, 2048, 512, 512);

    // --- LSTM scan (single persistent launch; R13 barrier) ---
    lstm_init_kernel<<<dim3(64), 256, 0, stream>>>(h0, HA, bar);
    lstm_scan_kernel<<<dim3(64), 256, 0, stream>>>(
        whh_b, wih_b, bih, bhh, HA, c0, hfc2_b, done, feat_b,
        out + 131072, out + 131072 + 16384, bar);

    // --- discriminator head ---
    gemm_bf16_kernel<true, false, true><<<dim3(2, 32), 256, 0, stream>>>(
        feat_b, dfw_b, dfb, nullptr, dfeat_b, 2048, 128, 512);
    gemm_bf16_kernel<false, false, false><<<dim3(1, 32), 256, 0, stream>>>(
        dfeat_b, dw_b, db, nullptr, out, 2048, 64, 128);
}